// Round 8
// baseline (1118.505 us; speedup 1.0000x reference)
//
#include <hip/hip_runtime.h>

// APPNP: h0 = relu(x@W1+b1)@W2+b2 ; 10x h = 0.99*SpMM(h) + 0.01*h
// bf16 MFMA GEMMs, on-device CSR build, gather SpMM with bf16 h storage.
// R6/R7: cross-XCD shared-line writes amplify ~8x; nt hints all bad.
// R9: device-scope atomicAdd is write-through past L2 (~30B fabric write
//     per atomic, ~26G/s cap); only atomic COUNT matters.
// R10: atomic-minimized CSR build — 1492 -> 1201 us.
// R11: gemm1 tiled+LDS (latency-bound fix) — 1201 -> 1107 us. Top-5 now
//     all harness workspace-poison fills (800MB, outside dur_us) — our
//     kernels are masked; budget arithmetic: prop ~10x85us dominates.
// R12: prop MLP probe/fix. Loop was colw->gather dependent chain,
//     unroll 2 => ~2 outstanding gathers/wave; 32 waves/CU x 2 / 600cyc
//     x 256CU ~= the observed ~4.8 TB/s gather rate => latency-bound
//     hypothesis. Main loop now processes 32 edges with 4 independent
//     colw+gather chains (static reg indexing, no runtime-indexed
//     arrays). Pre-committed read: -25..35% on prop => latency-bound
//     confirmed; neutral => LLC-BW-bound => next round col-chunked SpMM.

#define N_NODES 100000
#define N_EDGES 3200000
#define IN_F    512
#define HID_F   256
#define OUT_F   64
#define NBKT    ((N_NODES + 63) / 64)   // 1563 coarse buckets (row>>6)
#define CAP     4096                     // slots per bucket segment
#define SBLK    250                      // scatter blocks
#define SCHUNK  12800                    // edges per scatter block

#define BM 128
#define BN 128
#define BK 32
#define LDK 40                           // padded LDS row (bf16 elems)

typedef short bf16x8 __attribute__((ext_vector_type(8)));
typedef float f32x4  __attribute__((ext_vector_type(4)));

__device__ __forceinline__ unsigned short f2bf(float f) {
    unsigned int u = __float_as_uint(f);
    unsigned int r = (u + 0x7FFFu + ((u >> 16) & 1u)) >> 16;  // RNE
    return (unsigned short)r;
}
__device__ __forceinline__ float bf2f(unsigned short h) {
    return __uint_as_float(((unsigned int)h) << 16);
}

// ---------------- weight cast+transpose ----------------
__global__ void cast_transpose_w1(const float* __restrict__ w, unsigned short* __restrict__ wt) {
    int idx = blockIdx.x * blockDim.x + threadIdx.x;   // over 512*256
    if (idx >= IN_F * HID_F) return;
    int k = idx / HID_F, n = idx % HID_F;
    wt[(size_t)n * IN_F + k] = f2bf(w[idx]);           // W1T [HID_F][IN_F]
}
__global__ void cast_transpose_w2(const float* __restrict__ w, unsigned short* __restrict__ wt) {
    int idx = blockIdx.x * blockDim.x + threadIdx.x;   // over 256*64
    if (idx >= HID_F * OUT_F) return;
    int k = idx / OUT_F, n = idx % OUT_F;
    wt[(size_t)n * HID_F + k] = f2bf(w[idx]);          // W2T [OUT_F][HID_F]
}

// ---------------- x cast: fp32 -> bf16, coalesced stream ----------------
__global__ __launch_bounds__(256) void cast_x(const float* __restrict__ x,
                                              unsigned short* __restrict__ xb) {
    int idx = blockIdx.x * 256 + threadIdx.x;          // octet index, 6.4M total
    if (idx >= N_NODES * IN_F / 8) return;
    const float4* s = (const float4*)(x + (size_t)idx * 8);
    float4 f0 = s[0], f1 = s[1];
    union { bf16x8 v; unsigned short u[8]; } t;
    t.u[0] = f2bf(f0.x); t.u[1] = f2bf(f0.y); t.u[2] = f2bf(f0.z); t.u[3] = f2bf(f0.w);
    t.u[4] = f2bf(f1.x); t.u[5] = f2bf(f1.y); t.u[6] = f2bf(f1.z); t.u[7] = f2bf(f1.w);
    *(bf16x8*)(xb + (size_t)idx * 8) = t.v;
}

// ---------------- GEMM1: h1 = relu(xb @ W1 + b1), tiled+LDS ----------------
// grid: (ceil(M/128)) * 2 blocks; blockIdx>>1 = m-tile, blockIdx&1 = n-half.
__global__ __launch_bounds__(256) void gemm1(const unsigned short* __restrict__ xb,
                                             const unsigned short* __restrict__ w1t,
                                             const float* __restrict__ b1,
                                             unsigned short* __restrict__ h1) {
    __shared__ unsigned short lA[2][BM][LDK];
    __shared__ unsigned short lB[2][BN][LDK];

    int tid  = threadIdx.x;
    int bm0  = (blockIdx.x >> 1) * BM;
    int n0   = (blockIdx.x & 1) * BN;
    int lane = tid & 63;
    int w    = tid >> 6;      // 0..3
    int wm   = w >> 1;        // 0..1
    int wn   = w & 1;         // 0..1
    int quad = lane >> 4;     // 0..3
    int lm   = lane & 15;

    int sr = tid >> 2;        // 0..63
    int sq = (tid & 3) * 8;

    f32x4 acc[4][4];
    #pragma unroll
    for (int i = 0; i < 4; ++i)
        #pragma unroll
        for (int j = 0; j < 4; ++j)
            acc[i][j] = (f32x4){0.f, 0.f, 0.f, 0.f};

    bf16x8 ra[2], rb[2];
    #pragma unroll
    for (int j = 0; j < 2; ++j) {
        int m = bm0 + sr + j * 64; if (m > N_NODES - 1) m = N_NODES - 1;
        ra[j] = *(const bf16x8*)(xb  + (size_t)m * IN_F + sq);
        rb[j] = *(const bf16x8*)(w1t + (size_t)(n0 + sr + j * 64) * IN_F + sq);
    }
    #pragma unroll
    for (int j = 0; j < 2; ++j) {
        *(bf16x8*)&lA[0][sr + j * 64][sq] = ra[j];
        *(bf16x8*)&lB[0][sr + j * 64][sq] = rb[j];
    }
    __syncthreads();

    int cur = 0;
    for (int step = 0; step < IN_F / BK; ++step) {
        if (step + 1 < IN_F / BK) {
            int kn = (step + 1) * BK;
            #pragma unroll
            for (int j = 0; j < 2; ++j) {
                int m = bm0 + sr + j * 64; if (m > N_NODES - 1) m = N_NODES - 1;
                ra[j] = *(const bf16x8*)(xb  + (size_t)m * IN_F + kn + sq);
                rb[j] = *(const bf16x8*)(w1t + (size_t)(n0 + sr + j * 64) * IN_F + kn + sq);
            }
        }
        bf16x8 af[4], bfr[4];
        #pragma unroll
        for (int i = 0; i < 4; ++i)
            af[i] = *(const bf16x8*)&lA[cur][wm * 64 + i * 16 + lm][quad * 8];
        #pragma unroll
        for (int j = 0; j < 4; ++j)
            bfr[j] = *(const bf16x8*)&lB[cur][wn * 64 + j * 16 + lm][quad * 8];
        #pragma unroll
        for (int i = 0; i < 4; ++i)
            #pragma unroll
            for (int j = 0; j < 4; ++j)
                acc[i][j] = __builtin_amdgcn_mfma_f32_16x16x32_bf16(af[i], bfr[j], acc[i][j], 0, 0, 0);
        if (step + 1 < IN_F / BK) {
            #pragma unroll
            for (int j = 0; j < 2; ++j) {
                *(bf16x8*)&lA[cur ^ 1][sr + j * 64][sq] = ra[j];
                *(bf16x8*)&lB[cur ^ 1][sr + j * 64][sq] = rb[j];
            }
            __syncthreads();
            cur ^= 1;
        }
    }

    #pragma unroll
    for (int i = 0; i < 4; ++i)
        #pragma unroll
        for (int j = 0; j < 4; ++j) {
            int n = n0 + wn * 64 + j * 16 + lm;
            float bias = b1[n];
            #pragma unroll
            for (int r = 0; r < 4; ++r) {
                int m = bm0 + wm * 64 + i * 16 + quad * 4 + r;
                if (m < N_NODES) {
                    float v = acc[i][j][r] + bias;
                    v = v > 0.f ? v : 0.f;
                    h1[(size_t)m * HID_F + n] = f2bf(v);
                }
            }
        }
}

// ---------------- GEMM2: h0 = h1 @ W2 + b2, bf16 out ----------------
__global__ __launch_bounds__(256) void gemm2(const unsigned short* __restrict__ h1,
                                             const unsigned short* __restrict__ w2t,
                                             const float* __restrict__ b2,
                                             unsigned short* __restrict__ h0) {
    int tid  = threadIdx.x;
    int lane = tid & 63;
    int w    = tid >> 6;     // 0..3
    int wm   = w >> 1;       // 0..1
    int wn   = w & 1;        // 0..1
    int quad = lane >> 4;
    int lm   = lane & 15;
    int m0 = blockIdx.x * 64 + wm * 32;
    int n0 = wn * 32;

    f32x4 acc[2][2];
    for (int i = 0; i < 2; ++i)
        for (int j = 0; j < 2; ++j)
            acc[i][j] = (f32x4){0.f, 0.f, 0.f, 0.f};

    for (int kk = 0; kk < HID_F; kk += 32) {
        bf16x8 a[2], b[2];
        for (int i = 0; i < 2; ++i) {
            int m = m0 + i * 16 + lm;
            if (m > N_NODES - 1) m = N_NODES - 1;
            a[i] = *(const bf16x8*)(h1 + (size_t)m * HID_F + kk + quad * 8);
        }
        for (int j = 0; j < 2; ++j) {
            int n = n0 + j * 16 + lm;
            b[j] = *(const bf16x8*)(w2t + (size_t)n * HID_F + kk + quad * 8);
        }
        for (int i = 0; i < 2; ++i)
            for (int j = 0; j < 2; ++j)
                acc[i][j] = __builtin_amdgcn_mfma_f32_16x16x32_bf16(a[i], b[j], acc[i][j], 0, 0, 0);
    }

    for (int i = 0; i < 2; ++i)
        for (int j = 0; j < 2; ++j) {
            int n = n0 + j * 16 + lm;
            float bias = b2[n];
            for (int r = 0; r < 4; ++r) {
                int m = m0 + i * 16 + quad * 4 + r;
                if (m < N_NODES) {
                    float v = acc[i][j][r] + bias;
                    h0[(size_t)m * OUT_F + n] = f2bf(v);
                }
            }
        }
}

// ---------------- CSR build (atomic-minimized) ----------------
__global__ void bs_init(int* __restrict__ cur) {
    int c = blockIdx.x * blockDim.x + threadIdx.x;
    if (c < NBKT) cur[c] = c * CAP;
}

__global__ __launch_bounds__(256) void bucket_scatter(const int* __restrict__ row,
                                                      const int* __restrict__ col,
                                                      const float* __restrict__ ew,
                                                      int* __restrict__ cur,
                                                      uint2* __restrict__ tmp) {
    __shared__ int lh[NBKT];   // histogram, then reserved base
    __shared__ int lc[NBKT];   // local cursor
    int tid = threadIdx.x;
    int e0 = blockIdx.x * SCHUNK;

    for (int c = tid; c < NBKT; c += 256) { lh[c] = 0; lc[c] = 0; }
    __syncthreads();
    for (int i = tid; i < SCHUNK; i += 256)
        atomicAdd(&lh[row[e0 + i] >> 6], 1);
    __syncthreads();
    for (int c = tid; c < NBKT; c += 256) {
        int n = lh[c];
        if (n) lh[c] = atomicAdd(&cur[c], n);   // lh[c] becomes global base
    }
    __syncthreads();
    for (int i = tid; i < SCHUNK; i += 256) {
        int e = e0 + i;
        int r = row[e];
        int c = r >> 6;
        int p = lh[c] + atomicAdd(&lc[c], 1);
        if (p < (c + 1) * CAP)   // safety clamp (CAP=4096 vs mean 2048)
            tmp[p] = make_uint2((unsigned)col[e] | ((unsigned)(r & 63) << 17),
                                __float_as_uint(ew[e]));
    }
}

__global__ __launch_bounds__(64) void bkt_scan(const int* __restrict__ cur,
                                               int* __restrict__ bktbase,
                                               int* __restrict__ rowptr) {
    int lane = threadIdx.x;
    int carry = 0;
    for (int base = 0; base < NBKT; base += 64) {
        int c = base + lane;
        int v = (c < NBKT) ? (cur[c] - c * CAP) : 0;
        int incl = v;
        for (int d = 1; d < 64; d <<= 1) {
            int t = __shfl_up(incl, d);
            if (lane >= d) incl += t;
        }
        if (c < NBKT) bktbase[c] = carry + incl - v;
        carry += __shfl(incl, 63);
    }
    if (lane == 0) { bktbase[NBKT] = carry; rowptr[N_NODES] = carry; }
}

__global__ __launch_bounds__(256) void bucket_sort(const uint2* __restrict__ tmp,
                                                   const int* __restrict__ bktbase,
                                                   int* __restrict__ rowptr,
                                                   int2* __restrict__ colw) {
    __shared__ int rh[64];
    __shared__ int lcur[64];
    int c = blockIdx.x;
    int tid = threadIdx.x;
    int s = c * CAP;
    int base = bktbase[c];
    int tot = bktbase[c + 1] - base;

    if (tid < 64) rh[tid] = 0;
    __syncthreads();
    for (int i = tid; i < tot; i += 256)
        atomicAdd(&rh[(tmp[s + i].x >> 17) & 63], 1);
    __syncthreads();
    if (tid < 64) {
        int v = rh[tid];
        int incl = v;
        for (int d = 1; d < 64; d <<= 1) {
            int t = __shfl_up(incl, d);
            if (tid >= d) incl += t;
        }
        int excl = incl - v;
        int rr = c * 64 + tid;
        if (rr < N_NODES) rowptr[rr] = base + excl;
        lcur[tid] = base + excl;
    }
    __syncthreads();
    for (int i = tid; i < tot; i += 256) {
        uint2 t = tmp[s + i];
        int rl = (t.x >> 17) & 63;
        int p = atomicAdd(&lcur[rl], 1);
        colw[p] = make_int2((int)(t.x & 0x1FFFF), (int)t.y);
    }
}

// ---------------- propagation ----------------
// One wave per row. 64 lanes = 8 edge-slots x 8 feature-octets.
// R12: main loop takes 32 edges/iter with 4 INDEPENDENT colw->gather
// chains (explicit MLP=4/wave); 8-edge mid loop; scalar tail. All
// register indexing static (rule: runtime-indexed arrays spill).
__global__ __launch_bounds__(256) void prop(const unsigned short* __restrict__ hin,
                                            const int* __restrict__ rowptr,
                                            const int2* __restrict__ colw,
                                            unsigned short* __restrict__ hout,
                                            float* __restrict__ fout, int is_final) {
    int lane = threadIdx.x & 63;
    int r = blockIdx.x * 4 + (threadIdx.x >> 6);
    int fe   = lane & 7;     // feature octet index
    int slot = lane >> 3;    // 0..7

    int s = rowptr[r];
    int e = rowptr[r + 1];
    const unsigned short* hfe = hin + 8 * fe;

    float af[8];
    #pragma unroll
    for (int k = 0; k < 8; ++k) af[k] = 0.f;

    int i = s;
    // main: 32 edges per iteration, 4 independent chains
    for (; i + 32 <= e; i += 32) {
        int2 c0 = colw[i + slot];
        int2 c1 = colw[i + 8 + slot];
        int2 c2 = colw[i + 16 + slot];
        int2 c3 = colw[i + 24 + slot];
        bf16x8 p0 = *(const bf16x8*)(hfe + (unsigned)c0.x * (unsigned)OUT_F);
        bf16x8 p1 = *(const bf16x8*)(hfe + (unsigned)c1.x * (unsigned)OUT_F);
        bf16x8 p2 = *(const bf16x8*)(hfe + (unsigned)c2.x * (unsigned)OUT_F);
        bf16x8 p3 = *(const bf16x8*)(hfe + (unsigned)c3.x * (unsigned)OUT_F);
        float w0 = __int_as_float(c0.y);
        float w1 = __int_as_float(c1.y);
        float w2 = __int_as_float(c2.y);
        float w3 = __int_as_float(c3.y);
        #pragma unroll
        for (int k = 0; k < 8; ++k) {
            af[k] += w0 * bf2f((unsigned short)p0[k]);
            af[k] += w1 * bf2f((unsigned short)p1[k]);
            af[k] += w2 * bf2f((unsigned short)p2[k]);
            af[k] += w3 * bf2f((unsigned short)p3[k]);
        }
    }
    // mid: 8 edges per iteration
    for (; i + 8 <= e; i += 8) {
        int2 cw = colw[i + slot];
        float w = __int_as_float(cw.y);
        bf16x8 p = *(const bf16x8*)(hfe + (unsigned)cw.x * (unsigned)OUT_F);
        #pragma unroll
        for (int k = 0; k < 8; ++k)
            af[k] += w * bf2f((unsigned short)p[k]);
    }
    {   // tail (0..7 edges)
        int ei = i + slot;
        if (ei < e) {
            int2 cw = colw[ei];
            float w = __int_as_float(cw.y);
            bf16x8 p = *(const bf16x8*)(hfe + (unsigned)cw.x * (unsigned)OUT_F);
            #pragma unroll
            for (int k = 0; k < 8; ++k)
                af[k] += w * bf2f((unsigned short)p[k]);
        }
    }
    // combine the 8 edge-slots
    #pragma unroll
    for (int k = 0; k < 8; ++k) {
        af[k] += __shfl_xor(af[k], 8);
        af[k] += __shfl_xor(af[k], 16);
        af[k] += __shfl_xor(af[k], 32);
    }

    if (slot == 0) {
        bf16x8 ps = *(const bf16x8*)(hin + (unsigned)r * (unsigned)OUT_F + 8 * fe);
        float rr[8];
        #pragma unroll
        for (int k = 0; k < 8; ++k)
            rr[k] = 0.99f * af[k] + 0.01f * bf2f((unsigned short)ps[k]);
        size_t o = (size_t)r * OUT_F + 8 * fe;
        if (is_final) {
            *(float4*)(fout + o)     = make_float4(rr[0], rr[1], rr[2], rr[3]);
            *(float4*)(fout + o + 4) = make_float4(rr[4], rr[5], rr[6], rr[7]);
        } else {
            union { bf16x8 v; unsigned short u[8]; } pk;
            #pragma unroll
            for (int k = 0; k < 8; ++k) pk.u[k] = f2bf(rr[k]);
            *(bf16x8*)(hout + o) = pk.v;
        }
    }
}

extern "C" void kernel_launch(void* const* d_in, const int* in_sizes, int n_in,
                              void* d_out, int out_size, void* d_ws, size_t ws_size,
                              hipStream_t stream) {
    (void)in_sizes; (void)n_in; (void)out_size; (void)ws_size;
    const float* x  = (const float*)d_in[0];
    const float* W1 = (const float*)d_in[1];
    const float* b1 = (const float*)d_in[2];
    const float* W2 = (const float*)d_in[3];
    const float* b2 = (const float*)d_in[4];
    const float* ew = (const float*)d_in[5];
    const int*  row = (const int*)d_in[6];
    const int*  col = (const int*)d_in[7];
    float* out = (float*)d_out;

    char* ws = (char*)d_ws;
    size_t off = 0;
    auto alloc = [&](size_t b) { char* p = ws + off; off += (b + 255) & ~(size_t)255; return p; };
    // Region A: xb (102.4MB, lifetime cast_x..gemm1) aliases
    // tmp (CAP segments, 51.2MB) + colw (25.6MB), lifetime scatter..end.
    char* regionA = alloc((size_t)N_NODES * IN_F * 2);
    unsigned short* xb  = (unsigned short*)regionA;
    uint2* tmp  = (uint2*)regionA;
    int2*  colw = (int2*)(regionA + (size_t)NBKT * CAP * 8);
    unsigned short* w1t = (unsigned short*)alloc((size_t)IN_F * HID_F * 2);
    unsigned short* w2t = (unsigned short*)alloc((size_t)HID_F * OUT_F * 2);
    unsigned short* h1  = (unsigned short*)alloc((size_t)N_NODES * HID_F * 2);
    unsigned short* hb0 = (unsigned short*)alloc((size_t)N_NODES * OUT_F * 2);
    unsigned short* hb1 = (unsigned short*)alloc((size_t)N_NODES * OUT_F * 2);
    int*  rowptr  = (int*)alloc((size_t)(N_NODES + 1) * 4);
    int*  cur     = (int*)alloc((size_t)NBKT * 4);
    int*  bktbase = (int*)alloc((size_t)(NBKT + 1) * 4);

    cast_transpose_w1<<<(IN_F * HID_F + 255) / 256, 256, 0, stream>>>(W1, w1t);
    cast_transpose_w2<<<(HID_F * OUT_F + 255) / 256, 256, 0, stream>>>(W2, w2t);
    cast_x<<<(N_NODES * IN_F / 8 + 255) / 256, 256, 0, stream>>>(x, xb);
    gemm1<<<((N_NODES + BM - 1) / BM) * 2, 256, 0, stream>>>(xb, w1t, b1, h1);
    gemm2<<<(N_NODES + 63) / 64, 256, 0, stream>>>(h1, w2t, b2, hb0);

    bs_init<<<(NBKT + 255) / 256, 256, 0, stream>>>(cur);
    bucket_scatter<<<SBLK, 256, 0, stream>>>(row, col, ew, cur, tmp);
    bkt_scan<<<1, 64, 0, stream>>>(cur, bktbase, rowptr);
    bucket_sort<<<NBKT, 256, 0, stream>>>(tmp, bktbase, rowptr, colw);

    const unsigned short* pin = hb0;
    for (int s = 0; s < 10; ++s) {
        int last = (s == 9);
        unsigned short* pout = (s & 1) ? hb0 : hb1;
        prop<<<N_NODES / 4, 256, 0, stream>>>(pin, rowptr, colw, pout, out, last);
        pin = pout;
    }
}